// Round 1
// baseline (1842.929 us; speedup 1.0000x reference)
//
#include <hip/hip_runtime.h>
#include <hip/hip_bf16.h>

#define H 128

static inline size_t align_up(size_t x, size_t a){ return (x + a - 1) & ~(a - 1); }

// ---------------- degree counting ----------------
__global__ void count_kernel(const int* __restrict__ src, const int* __restrict__ dst,
                             int* __restrict__ cnt_t, int* __restrict__ cnt_p, int E){
  int e = blockIdx.x * blockDim.x + threadIdx.x;
  if (e >= E) return;
  atomicAdd(&cnt_p[dst[e]], 1);
  atomicAdd(&cnt_t[src[e]], 1);
}

// ---------------- single-block exclusive scan + inv count ----------------
__global__ __launch_bounds__(1024) void scan_kernel(const int* __restrict__ cnt, int* __restrict__ off,
                            float* __restrict__ inv, int n){
  __shared__ int wsum[16];
  __shared__ int carry_s;
  int tid = threadIdx.x, lane = tid & 63, wid = tid >> 6;
  if (tid == 0) carry_s = 0;
  __syncthreads();
  const int PER = 4, CH = 1024 * PER;
  for (int start = 0; start < n; start += CH){
    int i0 = start + tid * PER;
    int v[PER]; int s = 0;
    #pragma unroll
    for (int q = 0; q < PER; q++){ int i = i0 + q; v[q] = (i < n) ? cnt[i] : 0; s += v[q]; }
    int sc = s;
    #pragma unroll
    for (int o2 = 1; o2 < 64; o2 <<= 1){ int t = __shfl_up(sc, (unsigned)o2, 64); if (lane >= o2) sc += t; }
    if (lane == 63) wsum[wid] = sc;
    __syncthreads();
    int base = carry_s;
    for (int w = 0; w < wid; ++w) base += wsum[w];
    int excl = base + sc - s;
    #pragma unroll
    for (int q = 0; q < PER; q++){
      int i = i0 + q;
      if (i < n){ off[i] = excl; inv[i] = 1.0f / (float)(v[q] > 1 ? v[q] : 1); }
      excl += v[q];
    }
    __syncthreads();
    if (tid == 1023) carry_s = base + sc;
    __syncthreads();
  }
  if (tid == 0) off[n] = carry_s;
}

// ---------------- CSR fill ----------------
__global__ void fill_csr(const int* __restrict__ src, const int* __restrict__ dst,
                         const int* __restrict__ off_p, const int* __restrict__ off_t,
                         int* __restrict__ cur_p, int* __restrict__ cur_t,
                         int* __restrict__ csr_p, int* __restrict__ csr_t, int E){
  int e = blockIdx.x * blockDim.x + threadIdx.x;
  if (e >= E) return;
  int s = src[e], d = dst[e];
  int pp = atomicAdd(&cur_p[d], 1);
  csr_p[off_p[d] + pp] = s;
  int pt = atomicAdd(&cur_t[s], 1);
  csr_t[off_t[s] + pt] = d;
}

// ---------------- input linear: Y[M,128] = X[M,K] @ W[K,128] + b ----------------
template<int K>
__global__ __launch_bounds__(128) void linear_kernel(const float* __restrict__ X, const float* __restrict__ W,
                              const float* __restrict__ bvec, float* __restrict__ Y, int M){
  const int R = 8;
  __shared__ float xs[R][K];
  int j = threadIdx.x;
  int row0 = blockIdx.x * R;
  for (int t = j; t < R * K; t += 128){
    int r = t / K, k = t - r * K;
    int row = row0 + r;
    xs[r][k] = (row < M) ? X[(size_t)row * K + k] : 0.f;
  }
  __syncthreads();
  float acc[R];
  float bb = bvec[j];
  #pragma unroll
  for (int r = 0; r < R; r++) acc[r] = bb;
  for (int k = 0; k < K; k++){
    float w = W[k * H + j];
    #pragma unroll
    for (int r = 0; r < R; r++) acc[r] = fmaf(xs[r][k], w, acc[r]);
  }
  #pragma unroll
  for (int r = 0; r < R; r++){
    int row = row0 + r;
    if (row < M) Y[(size_t)row * H + j] = acc[r];
  }
}

// ---------------- segment mean via CSR ----------------
__global__ __launch_bounds__(256) void agg_kernel(const float* __restrict__ feat, const int* __restrict__ csr,
                           const int* __restrict__ off, const float* __restrict__ inv,
                           float* __restrict__ out, int n){
  int gw = (int)((blockIdx.x * blockDim.x + threadIdx.x) >> 6);
  int lane = threadIdx.x & 63;
  if (gw >= n) return;
  int s = off[gw], e = off[gw + 1];
  float2 acc0 = {0.f, 0.f}, acc1 = {0.f, 0.f};
  int i = s;
  for (; i + 1 < e; i += 2){
    int i0 = csr[i], i1 = csr[i + 1];
    float2 a = *(const float2*)&feat[(size_t)i0 * H + lane * 2];
    float2 b = *(const float2*)&feat[(size_t)i1 * H + lane * 2];
    acc0.x += a.x; acc0.y += a.y;
    acc1.x += b.x; acc1.y += b.y;
  }
  if (i < e){
    int i0 = csr[i];
    float2 a = *(const float2*)&feat[(size_t)i0 * H + lane * 2];
    acc0.x += a.x; acc0.y += a.y;
  }
  float iv = inv[gw];
  float2 r; r.x = (acc0.x + acc1.x) * iv; r.y = (acc0.y + acc1.y) * iv;
  *(float2*)&out[(size_t)gw * H + lane * 2] = r;
}

// ---------------- fused SAGE transform (in-place safe) ----------------
template<bool RELU>
__global__ __launch_bounds__(128) void sage_kernel(const float* AGG, const float* Hs,
                            const float* __restrict__ Wl, const float* __restrict__ bvec,
                            const float* __restrict__ Wr, float* OUT, int M){
  const int R = 8;
  __shared__ float sa[R][H];
  __shared__ float sh[R][H];
  __shared__ float red[2][R];
  int j = threadIdx.x;
  int row0 = blockIdx.x * R;
  for (int t = j; t < R * H; t += 128){
    int r = t >> 7, k = t & 127;
    int row = row0 + r;
    sa[r][k] = (row < M) ? AGG[(size_t)row * H + k] : 0.f;
    sh[r][k] = (row < M) ? Hs[(size_t)row * H + k] : 0.f;
  }
  __syncthreads();
  float acc[R];
  float bb = bvec[j];
  #pragma unroll
  for (int r = 0; r < R; r++) acc[r] = bb;
  for (int k = 0; k < H; k++){
    float wl = Wl[k * H + j];
    float wr = Wr[k * H + j];
    #pragma unroll
    for (int r = 0; r < R; r++) acc[r] = fmaf(sa[r][k], wl, fmaf(sh[r][k], wr, acc[r]));
  }
  int lane = j & 63, wid = j >> 6;
  #pragma unroll
  for (int r = 0; r < R; r++){
    float v = acc[r] * acc[r];
    #pragma unroll
    for (int o = 32; o >= 1; o >>= 1) v += __shfl_xor(v, o, 64);
    if (lane == 0) red[wid][r] = v;
  }
  __syncthreads();
  #pragma unroll
  for (int r = 0; r < R; r++){
    int row = row0 + r;
    if (row >= M) continue;
    float s = red[0][r] + red[1][r];
    float scale = 1.0f / fmaxf(sqrtf(s), 1e-12f);
    float v = acc[r] * scale;
    if (RELU) v = fmaxf(v, 0.f);
    OUT[(size_t)row * H + j] = v;
  }
}

// ---------------- link predictor ----------------
__global__ __launch_bounds__(256) void dot_kernel(const float* __restrict__ zt, const float* __restrict__ zp,
                           const int* __restrict__ ls, const int* __restrict__ ld,
                           float* __restrict__ out, int n){
  int w = (int)((blockIdx.x * blockDim.x + threadIdx.x) >> 6);
  int lane = threadIdx.x & 63;
  if (w >= n) return;
  int a = ls[w], b = ld[w];
  float2 x = *(const float2*)&zt[(size_t)a * H + lane * 2];
  float2 y = *(const float2*)&zp[(size_t)b * H + lane * 2];
  float v = x.x * y.x + x.y * y.y;
  #pragma unroll
  for (int o = 32; o >= 1; o >>= 1) v += __shfl_xor(v, o, 64);
  if (lane == 0) out[w] = v;
}

extern "C" void kernel_launch(void* const* d_in, const int* in_sizes, int n_in,
                              void* d_out, int out_size, void* d_ws, size_t ws_size,
                              hipStream_t stream){
  const float* x_t  = (const float*)d_in[0];
  const float* x_p  = (const float*)d_in[1];
  const int*   esrc = (const int*)d_in[2];
  const int*   edst = (const int*)d_in[3];
  const int*   lsrc = (const int*)d_in[4];
  const int*   ldst = (const int*)d_in[5];
  const float* Wn_t = (const float*)d_in[6];
  const float* bn_t = (const float*)d_in[7];
  const float* Wn_p = (const float*)d_in[8];
  const float* bn_p = (const float*)d_in[9];
  const float* W1_l_p=(const float*)d_in[10]; const float* b1_p=(const float*)d_in[11]; const float* W1_r_p=(const float*)d_in[12];
  const float* W1_l_t=(const float*)d_in[13]; const float* b1_t=(const float*)d_in[14]; const float* W1_r_t=(const float*)d_in[15];
  const float* W2_l_p=(const float*)d_in[16]; const float* b2_p=(const float*)d_in[17]; const float* W2_r_p=(const float*)d_in[18];
  const float* W2_l_t=(const float*)d_in[19]; const float* b2_t=(const float*)d_in[20]; const float* W2_r_t=(const float*)d_in[21];
  float* out = (float*)d_out;

  const int FT = 128, FP = 64;
  int NT = in_sizes[0] / FT;
  int NP = in_sizes[1] / FP;
  int E  = in_sizes[2];
  int EL = in_sizes[4];

  char* base = (char*)d_ws;
  size_t o = 0;
  auto alloc = [&](size_t bytes) -> char* { char* p = base + o; o = align_up(o + bytes, 256); return p; };
  int*   cnt_p = (int*)alloc((size_t)NP * 4);
  int*   cnt_t = (int*)alloc((size_t)NT * 4);
  int*   cur_p = (int*)alloc((size_t)NP * 4);
  int*   cur_t = (int*)alloc((size_t)NT * 4);
  size_t zero_bytes = o;
  int*   off_p = (int*)alloc((size_t)(NP + 1) * 4);
  int*   off_t = (int*)alloc((size_t)(NT + 1) * 4);
  float* inv_p = (float*)alloc((size_t)NP * 4);
  float* inv_t = (float*)alloc((size_t)NT * 4);
  int*   csr_p = (int*)alloc((size_t)E * 4);   // src track idx grouped by playlist
  int*   csr_t = (int*)alloc((size_t)E * 4);   // dst playlist idx grouped by track
  float* h_t   = (float*)alloc((size_t)NT * H * 4);  // h_t -> agg_t2 -> z_t
  float* h_p   = (float*)alloc((size_t)NP * H * 4);  // h_p -> agg_p2 -> z_p
  float* a_t   = (float*)alloc((size_t)NT * H * 4);  // agg_t -> o_t (in-place)
  float* a_p   = (float*)alloc((size_t)NP * H * 4);  // agg_p -> o_p (in-place)
  (void)ws_size; (void)n_in; (void)out_size;

  hipMemsetAsync(base, 0, zero_bytes, stream);
  const int tb = 256;
  count_kernel<<<(E + tb - 1) / tb, tb, 0, stream>>>(esrc, edst, cnt_t, cnt_p, E);
  scan_kernel<<<1, 1024, 0, stream>>>(cnt_p, off_p, inv_p, NP);
  scan_kernel<<<1, 1024, 0, stream>>>(cnt_t, off_t, inv_t, NT);
  fill_csr<<<(E + tb - 1) / tb, tb, 0, stream>>>(esrc, edst, off_p, off_t, cur_p, cur_t, csr_p, csr_t, E);

  // input projections
  linear_kernel<128><<<(NT + 7) / 8, 128, 0, stream>>>(x_t, Wn_t, bn_t, h_t, NT);
  linear_kernel<64><<<(NP + 7) / 8, 128, 0, stream>>>(x_p, Wn_p, bn_p, h_p, NP);

  // layer 1: one wave per destination row, 4 waves per block
  agg_kernel<<<(NP + 3) / 4, 256, 0, stream>>>(h_t, csr_p, off_p, inv_p, a_p, NP);
  agg_kernel<<<(NT + 3) / 4, 256, 0, stream>>>(h_p, csr_t, off_t, inv_t, a_t, NT);
  sage_kernel<true><<<(NP + 7) / 8, 128, 0, stream>>>(a_p, h_p, W1_l_p, b1_p, W1_r_p, a_p, NP);
  sage_kernel<true><<<(NT + 7) / 8, 128, 0, stream>>>(a_t, h_t, W1_l_t, b1_t, W1_r_t, a_t, NT);

  // layer 2: aggs overwrite h buffers, transforms in-place
  agg_kernel<<<(NP + 3) / 4, 256, 0, stream>>>(a_t, csr_p, off_p, inv_p, h_p, NP);
  agg_kernel<<<(NT + 3) / 4, 256, 0, stream>>>(a_p, csr_t, off_t, inv_t, h_t, NT);
  sage_kernel<false><<<(NP + 7) / 8, 128, 0, stream>>>(h_p, a_p, W2_l_p, b2_p, W2_r_p, h_p, NP);
  sage_kernel<false><<<(NT + 7) / 8, 128, 0, stream>>>(h_t, a_t, W2_l_t, b2_t, W2_r_t, h_t, NT);

  // link prediction
  dot_kernel<<<(EL + 3) / 4, 256, 0, stream>>>(h_t, h_p, lsrc, ldst, out, EL);
}

// Round 2
// 1614.338 us; speedup vs baseline: 1.1416x; 1.1416x over previous
//
#include <hip/hip_runtime.h>
#include <hip/hip_bf16.h>

#define H 128

typedef __attribute__((ext_vector_type(8))) short bf16x8;
typedef __attribute__((ext_vector_type(4))) float f32x4;

static inline size_t align_up(size_t x, size_t a){ return (x + a - 1) & ~(a - 1); }

__device__ inline f32x4 mfma16(bf16x8 a, bf16x8 b, f32x4 c){
  return __builtin_amdgcn_mfma_f32_16x16x32_bf16(a, b, c, 0, 0, 0);
}

__device__ inline unsigned short bf_rne(float v){
  unsigned u = __float_as_uint(v);
  unsigned r = u + 0x7fffu + ((u >> 16) & 1u);
  return (unsigned short)(r >> 16);
}

__device__ inline void cvt_hilo(const f32x4& a0, const f32x4& a1, bf16x8& hi, bf16x8& lo){
  #pragma unroll
  for (int e = 0; e < 8; e++){
    float v = (e < 4) ? a0[e] : a1[e - 4];
    unsigned short hs = bf_rne(v);
    float hf = __uint_as_float((unsigned)hs << 16);
    hi[e] = (short)hs;
    lo[e] = (short)bf_rne(v - hf);
  }
}

// ---------------- degree counting ----------------
__global__ void count_kernel(const int* __restrict__ src, const int* __restrict__ dst,
                             int* __restrict__ cnt_t, int* __restrict__ cnt_p, int E){
  int e = blockIdx.x * blockDim.x + threadIdx.x;
  if (e >= E) return;
  atomicAdd(&cnt_p[dst[e]], 1);
  atomicAdd(&cnt_t[src[e]], 1);
}

// ---------------- single-block exclusive scan + inv count ----------------
__global__ __launch_bounds__(1024) void scan_kernel(const int* __restrict__ cnt, int* __restrict__ off,
                            float* __restrict__ inv, int n){
  __shared__ int wsum[16];
  __shared__ int carry_s;
  int tid = threadIdx.x, lane = tid & 63, wid = tid >> 6;
  if (tid == 0) carry_s = 0;
  __syncthreads();
  const int PER = 4, CH = 1024 * PER;
  for (int start = 0; start < n; start += CH){
    int i0 = start + tid * PER;
    int v[PER]; int s = 0;
    #pragma unroll
    for (int q = 0; q < PER; q++){ int i = i0 + q; v[q] = (i < n) ? cnt[i] : 0; s += v[q]; }
    int sc = s;
    #pragma unroll
    for (int o2 = 1; o2 < 64; o2 <<= 1){ int t = __shfl_up(sc, (unsigned)o2, 64); if (lane >= o2) sc += t; }
    if (lane == 63) wsum[wid] = sc;
    __syncthreads();
    int base = carry_s;
    for (int w = 0; w < wid; ++w) base += wsum[w];
    int excl = base + sc - s;
    #pragma unroll
    for (int q = 0; q < PER; q++){
      int i = i0 + q;
      if (i < n){ off[i] = excl; inv[i] = 1.0f / (float)(v[q] > 1 ? v[q] : 1); }
      excl += v[q];
    }
    __syncthreads();
    if (tid == 1023) carry_s = base + sc;
    __syncthreads();
  }
  if (tid == 0) off[n] = carry_s;
}

// ---------------- CSR fill ----------------
__global__ void fill_csr(const int* __restrict__ src, const int* __restrict__ dst,
                         const int* __restrict__ off_p, const int* __restrict__ off_t,
                         int* __restrict__ cur_p, int* __restrict__ cur_t,
                         int* __restrict__ csr_p, int* __restrict__ csr_t, int E){
  int e = blockIdx.x * blockDim.x + threadIdx.x;
  if (e >= E) return;
  int s = src[e], d = dst[e];
  int pp = atomicAdd(&cur_p[d], 1);
  csr_p[off_p[d] + pp] = s;
  int pt = atomicAdd(&cur_t[s], 1);
  csr_t[off_t[s] + pt] = d;
}

// ---------------- weight pre-pack: W[K][128] fp32 -> WT hi[128][K], lo[128][K] bf16 ----------------
struct PackArgs {
  const float* src[10];
  short* dst[10];
  int K[10];
  int start[11];
};
__global__ __launch_bounds__(256) void pack_w(PackArgs pa){
  int t = blockIdx.x * 256 + threadIdx.x;
  if (t >= pa.start[10]) return;
  int m = 0;
  #pragma unroll
  for (int i = 1; i < 10; i++) if (t >= pa.start[i]) m = i;
  int local = t - pa.start[m];
  int k = local >> 7, n = local & 127;
  float w = pa.src[m][local];
  unsigned short hs = bf_rne(w);
  float hf = __uint_as_float((unsigned)hs << 16);
  unsigned short ls = bf_rne(w - hf);
  short* d = pa.dst[m];
  int Km = pa.K[m];
  d[n * Km + k] = (short)hs;
  d[128 * Km + n * Km + k] = (short)ls;
}

// ---------------- fused MFMA GEMM: OUT = [relu?][l2norm?](A@Wl + bias [+ Bs@Wr]) ----------------
// 512 threads = 8 waves; wave w owns output cols [16w,16w+16); 16 rows per block-iter.
// W fragments (bf16 hi/lo, pre-transposed [col][k]) live in registers for the whole kernel.
// Split product: acc += Ahi*Whi + Ahi*Wlo + Alo*Whi  (error ~2^-16, ~fp32-equivalent).
template<int KA, bool DUAL, bool NORM, bool RELU>
__global__ __launch_bounds__(512) void sage_mfma(
    const float* __restrict__ A, const float* __restrict__ Bs,
    const short* __restrict__ WlT, const short* __restrict__ WrT,
    const float* __restrict__ bias, float* __restrict__ OUT, int M)
{
  constexpr int KST = KA / 32;
  const int wid  = threadIdx.x >> 6;
  const int lane = threadIdx.x & 63;
  const int l15  = lane & 15;
  const int lkg  = lane >> 4;
  const int ncol0 = wid * 16;

  bf16x8 wl_hi[KST], wl_lo[KST];
  {
    const short* bh = WlT + (size_t)(ncol0 + l15) * KA + lkg * 8;
    #pragma unroll
    for (int ks = 0; ks < KST; ks++){
      wl_hi[ks] = *(const bf16x8*)(bh + ks * 32);
      wl_lo[ks] = *(const bf16x8*)(bh + 128 * KA + ks * 32);
    }
  }
  bf16x8 wr_hi[DUAL ? KST : 1], wr_lo[DUAL ? KST : 1];
  if (DUAL){
    const short* bh = WrT + (size_t)(ncol0 + l15) * 128 + lkg * 8;
    #pragma unroll
    for (int ks = 0; ks < (DUAL ? KST : 1); ks++){
      wr_hi[ks] = *(const bf16x8*)(bh + ks * 32);
      wr_lo[ks] = *(const bf16x8*)(bh + 128 * 128 + ks * 32);
    }
  }
  const float bb = bias[ncol0 + l15];

  __shared__ float red[8][16];

  for (int row0 = blockIdx.x * 16; row0 < M; row0 += gridDim.x * 16){
    int ar = row0 + l15; if (ar > M - 1) ar = M - 1;
    f32x4 acc = {0.f, 0.f, 0.f, 0.f};
    {
      const float* ap = A + (size_t)ar * KA + lkg * 8;
      #pragma unroll
      for (int ks = 0; ks < KST; ks++){
        f32x4 a0 = *(const f32x4*)(ap + ks * 32);
        f32x4 a1 = *(const f32x4*)(ap + ks * 32 + 4);
        bf16x8 hi, lo;
        cvt_hilo(a0, a1, hi, lo);
        acc = mfma16(hi, wl_hi[ks], acc);
        acc = mfma16(hi, wl_lo[ks], acc);
        acc = mfma16(lo, wl_hi[ks], acc);
      }
    }
    if (DUAL){
      const float* bp = Bs + (size_t)ar * 128 + lkg * 8;
      #pragma unroll
      for (int ks = 0; ks < (DUAL ? KST : 1); ks++){
        f32x4 a0 = *(const f32x4*)(bp + ks * 32);
        f32x4 a1 = *(const f32x4*)(bp + ks * 32 + 4);
        bf16x8 hi, lo;
        cvt_hilo(a0, a1, hi, lo);
        acc = mfma16(hi, wr_hi[ks], acc);
        acc = mfma16(hi, wr_lo[ks], acc);
        acc = mfma16(lo, wr_hi[ks], acc);
      }
    }
    acc.x += bb; acc.y += bb; acc.z += bb; acc.w += bb;

    if (NORM){
      float s4[4];
      #pragma unroll
      for (int r = 0; r < 4; r++){
        float v = acc[r] * acc[r];
        v += __shfl_xor(v, 1, 64);
        v += __shfl_xor(v, 2, 64);
        v += __shfl_xor(v, 4, 64);
        v += __shfl_xor(v, 8, 64);
        s4[r] = v;                     // row = lkg*4 + r, same across the 16-lane group
      }
      if (l15 == 0){
        #pragma unroll
        for (int r = 0; r < 4; r++) red[wid][lkg * 4 + r] = s4[r];
      }
      __syncthreads();
      #pragma unroll
      for (int r = 0; r < 4; r++){
        float s = 0.f;
        #pragma unroll
        for (int w2 = 0; w2 < 8; w2++) s += red[w2][lkg * 4 + r];
        float scale = 1.f / fmaxf(sqrtf(s), 1e-12f);
        acc[r] *= scale;
      }
      __syncthreads();
    }
    if (RELU){
      acc.x = fmaxf(acc.x, 0.f); acc.y = fmaxf(acc.y, 0.f);
      acc.z = fmaxf(acc.z, 0.f); acc.w = fmaxf(acc.w, 0.f);
    }
    const int colg = ncol0 + l15;
    #pragma unroll
    for (int r = 0; r < 4; r++){
      int row = row0 + lkg * 4 + r;
      if (row < M) OUT[(size_t)row * H + colg] = acc[r];
    }
  }
}

// ---------------- segment mean via CSR: half-wave (32 lanes x float4) per dst row ----------------
__global__ __launch_bounds__(256) void agg_kernel(const float* __restrict__ feat, const int* __restrict__ csr,
                           const int* __restrict__ off, const float* __restrict__ inv,
                           float* __restrict__ out, int n){
  int gw = (blockIdx.x * 256 + threadIdx.x) >> 5;
  int li = threadIdx.x & 31;
  if (gw >= n) return;
  int s = off[gw], e = off[gw + 1];
  f32x4 acc0 = {0.f,0.f,0.f,0.f}, acc1 = {0.f,0.f,0.f,0.f};
  int i = s;
  for (; i + 1 < e; i += 2){
    int i0 = csr[i], i1 = csr[i + 1];
    f32x4 a = *(const f32x4*)&feat[(size_t)i0 * H + li * 4];
    f32x4 b = *(const f32x4*)&feat[(size_t)i1 * H + li * 4];
    acc0 += a; acc1 += b;
  }
  if (i < e){
    f32x4 a = *(const f32x4*)&feat[(size_t)csr[i] * H + li * 4];
    acc0 += a;
  }
  float iv = inv[gw];
  f32x4 r = (acc0 + acc1);
  r.x *= iv; r.y *= iv; r.z *= iv; r.w *= iv;
  *(f32x4*)&out[(size_t)gw * H + li * 4] = r;
}

// ---------------- link predictor: half-wave per pair ----------------
__global__ __launch_bounds__(256) void dot_kernel(const float* __restrict__ zt, const float* __restrict__ zp,
                           const int* __restrict__ ls, const int* __restrict__ ld,
                           float* __restrict__ out, int n){
  int w = (blockIdx.x * 256 + threadIdx.x) >> 5;
  int li = threadIdx.x & 31;
  if (w >= n) return;
  int a = ls[w], b = ld[w];
  f32x4 x = *(const f32x4*)&zt[(size_t)a * H + li * 4];
  f32x4 y = *(const f32x4*)&zp[(size_t)b * H + li * 4];
  float v = x.x * y.x + x.y * y.y + x.z * y.z + x.w * y.w;
  v += __shfl_xor(v, 1, 64);
  v += __shfl_xor(v, 2, 64);
  v += __shfl_xor(v, 4, 64);
  v += __shfl_xor(v, 8, 64);
  v += __shfl_xor(v, 16, 64);
  if (li == 0) out[w] = v;
}

extern "C" void kernel_launch(void* const* d_in, const int* in_sizes, int n_in,
                              void* d_out, int out_size, void* d_ws, size_t ws_size,
                              hipStream_t stream){
  const float* x_t  = (const float*)d_in[0];
  const float* x_p  = (const float*)d_in[1];
  const int*   esrc = (const int*)d_in[2];
  const int*   edst = (const int*)d_in[3];
  const int*   lsrc = (const int*)d_in[4];
  const int*   ldst = (const int*)d_in[5];
  const float* Wn_t = (const float*)d_in[6];
  const float* bn_t = (const float*)d_in[7];
  const float* Wn_p = (const float*)d_in[8];
  const float* bn_p = (const float*)d_in[9];
  const float* W1_l_p=(const float*)d_in[10]; const float* b1_p=(const float*)d_in[11]; const float* W1_r_p=(const float*)d_in[12];
  const float* W1_l_t=(const float*)d_in[13]; const float* b1_t=(const float*)d_in[14]; const float* W1_r_t=(const float*)d_in[15];
  const float* W2_l_p=(const float*)d_in[16]; const float* b2_p=(const float*)d_in[17]; const float* W2_r_p=(const float*)d_in[18];
  const float* W2_l_t=(const float*)d_in[19]; const float* b2_t=(const float*)d_in[20]; const float* W2_r_t=(const float*)d_in[21];
  float* out = (float*)d_out;

  const int FT = 128, FP = 64;
  int NT = in_sizes[0] / FT;
  int NP = in_sizes[1] / FP;
  int E  = in_sizes[2];
  int EL = in_sizes[4];

  char* base = (char*)d_ws;
  size_t o = 0;
  auto alloc = [&](size_t bytes) -> char* { char* p = base + o; o = align_up(o + bytes, 256); return p; };
  int*   cnt_p = (int*)alloc((size_t)NP * 4);
  int*   cnt_t = (int*)alloc((size_t)NT * 4);
  int*   cur_p = (int*)alloc((size_t)NP * 4);
  int*   cur_t = (int*)alloc((size_t)NT * 4);
  size_t zero_bytes = o;
  int*   off_p = (int*)alloc((size_t)(NP + 1) * 4);
  int*   off_t = (int*)alloc((size_t)(NT + 1) * 4);
  float* inv_p = (float*)alloc((size_t)NP * 4);
  float* inv_t = (float*)alloc((size_t)NT * 4);
  int*   csr_p = (int*)alloc((size_t)E * 4);
  int*   csr_t = (int*)alloc((size_t)E * 4);
  float* h_t   = (float*)alloc((size_t)NT * H * 4);
  float* h_p   = (float*)alloc((size_t)NP * H * 4);
  float* a_t   = (float*)alloc((size_t)NT * H * 4);
  float* a_p   = (float*)alloc((size_t)NP * H * 4);

  // packed weights: per matrix hi[128][K] then lo[128][K], bf16 (as short)
  PackArgs pa;
  const float* wsrc[10] = {Wn_t, Wn_p, W1_l_p, W1_r_p, W1_l_t, W1_r_t, W2_l_p, W2_r_p, W2_l_t, W2_r_t};
  int Ks[10] = {128, 64, 128, 128, 128, 128, 128, 128, 128, 128};
  short* wpk[10];
  int st = 0;
  for (int m = 0; m < 10; m++){
    wpk[m] = (short*)alloc((size_t)2 * 128 * Ks[m] * sizeof(short));
    pa.src[m] = wsrc[m]; pa.dst[m] = wpk[m]; pa.K[m] = Ks[m]; pa.start[m] = st;
    st += Ks[m] * 128;
  }
  pa.start[10] = st;
  (void)ws_size; (void)n_in; (void)out_size;

  hipMemsetAsync(base, 0, zero_bytes, stream);
  const int tb = 256;
  pack_w<<<(st + 255) / 256, 256, 0, stream>>>(pa);
  count_kernel<<<(E + tb - 1) / tb, tb, 0, stream>>>(esrc, edst, cnt_t, cnt_p, E);
  scan_kernel<<<1, 1024, 0, stream>>>(cnt_p, off_p, inv_p, NP);
  scan_kernel<<<1, 1024, 0, stream>>>(cnt_t, off_t, inv_t, NT);
  fill_csr<<<(E + tb - 1) / tb, tb, 0, stream>>>(esrc, edst, off_p, off_t, cur_p, cur_t, csr_p, csr_t, E);

  // input projections
  sage_mfma<128,false,false,false><<<(NT + 15) / 16, 512, 0, stream>>>(x_t, nullptr, wpk[0], nullptr, bn_t, h_t, NT);
  sage_mfma<64, false,false,false><<<(NP + 15) / 16, 512, 0, stream>>>(x_p, nullptr, wpk[1], nullptr, bn_p, h_p, NP);

  // layer 1
  agg_kernel<<<(NP + 7) / 8, 256, 0, stream>>>(h_t, csr_p, off_p, inv_p, a_p, NP);
  agg_kernel<<<(NT + 7) / 8, 256, 0, stream>>>(h_p, csr_t, off_t, inv_t, a_t, NT);
  sage_mfma<128,true,true,true><<<(NP + 15) / 16, 512, 0, stream>>>(a_p, h_p, wpk[2], wpk[3], b1_p, a_p, NP);
  sage_mfma<128,true,true,true><<<(NT + 15) / 16, 512, 0, stream>>>(a_t, h_t, wpk[4], wpk[5], b1_t, a_t, NT);

  // layer 2
  agg_kernel<<<(NP + 7) / 8, 256, 0, stream>>>(a_t, csr_p, off_p, inv_p, h_p, NP);
  agg_kernel<<<(NT + 7) / 8, 256, 0, stream>>>(a_p, csr_t, off_t, inv_t, h_t, NT);
  sage_mfma<128,true,true,false><<<(NP + 15) / 16, 512, 0, stream>>>(h_p, a_p, wpk[6], wpk[7], b2_p, h_p, NP);
  sage_mfma<128,true,true,false><<<(NT + 15) / 16, 512, 0, stream>>>(h_t, a_t, wpk[8], wpk[9], b2_t, h_t, NT);

  // link prediction
  dot_kernel<<<(EL + 7) / 8, 256, 0, stream>>>(h_t, h_p, lsrc, ldst, out, EL);
}

// Round 3
// 1246.467 us; speedup vs baseline: 1.4785x; 1.2951x over previous
//
#include <hip/hip_runtime.h>
#include <hip/hip_bf16.h>

#define H 128

typedef __attribute__((ext_vector_type(8))) short bf16x8;
typedef __attribute__((ext_vector_type(4))) float f32x4;

static inline size_t align_up(size_t x, size_t a){ return (x + a - 1) & ~(a - 1); }

__device__ inline f32x4 mfma16(bf16x8 a, bf16x8 b, f32x4 c){
  return __builtin_amdgcn_mfma_f32_16x16x32_bf16(a, b, c, 0, 0, 0);
}

__device__ inline unsigned short bf_rne(float v){
  unsigned u = __float_as_uint(v);
  unsigned r = u + 0x7fffu + ((u >> 16) & 1u);
  return (unsigned short)(r >> 16);
}

__device__ inline void cvt_hilo(const f32x4& a0, const f32x4& a1, bf16x8& hi, bf16x8& lo){
  #pragma unroll
  for (int e = 0; e < 8; e++){
    float v = (e < 4) ? a0[e] : a1[e - 4];
    unsigned short hs = bf_rne(v);
    float hf = __uint_as_float((unsigned)hs << 16);
    hi[e] = (short)hs;
    lo[e] = (short)bf_rne(v - hf);
  }
}

// ---------------- bucket histograms (coarse): dst>>7 (157 bins), src>>9 (196 bins) ----------------
__global__ __launch_bounds__(256) void hist_buckets(const int* __restrict__ src, const int* __restrict__ dst,
    int E, int* __restrict__ cnt_b_p, int* __restrict__ cnt_b_t){
  __shared__ int hp[256], ht[256];
  int tid = threadIdx.x;
  hp[tid] = 0; ht[tid] = 0;
  __syncthreads();
  for (int i = blockIdx.x * 256 + tid; i < E; i += gridDim.x * 256){
    atomicAdd(&hp[dst[i] >> 7], 1);
    atomicAdd(&ht[src[i] >> 9], 1);
  }
  __syncthreads();
  if (hp[tid]) atomicAdd(&cnt_b_p[tid], hp[tid]);
  if (ht[tid]) atomicAdd(&cnt_b_t[tid], ht[tid]);
}

// ---------------- tiny scan of bucket counts -> bases + cursors ----------------
__global__ void scan_buckets(const int* __restrict__ cb_p, const int* __restrict__ cb_t, int nbp, int nbt,
                             int* __restrict__ base_p, int* __restrict__ base_t,
                             int* __restrict__ cur_p, int* __restrict__ cur_t){
  if (threadIdx.x == 0){
    int s = 0;
    for (int i = 0; i < nbp; i++){ base_p[i] = s; cur_p[i] = s; s += cb_p[i]; }
    base_p[nbp] = s;
  } else if (threadIdx.x == 1){
    int s = 0;
    for (int i = 0; i < nbt; i++){ base_t[i] = s; cur_t[i] = s; s += cb_t[i]; }
    base_t[nbt] = s;
  }
}

// ---------------- bin edges into coarse buckets via per-block LDS counting sort ----------------
// record = (val << shift) | (key & ((1<<shift)-1)); chunk = 4096 edges per block.
__global__ __launch_bounds__(256) void bin_edges(const int* __restrict__ keys, const int* __restrict__ vals,
    int E, int shift, int nb, int* __restrict__ cursor, unsigned* __restrict__ rec_out){
  const int CH = 4096, IT = 16;
  __shared__ int hist[256];
  __shared__ int excl[256];
  __shared__ int gbase[256];
  __shared__ unsigned recs[CH];
  __shared__ unsigned char binid[CH];
  int tid = threadIdx.x;
  int start = blockIdx.x * CH;
  int cnt = E - start; if (cnt > CH) cnt = CH;
  if (cnt <= 0) return;
  hist[tid] = 0;
  __syncthreads();
  int b[IT]; int rank[IT]; unsigned rc[IT];
  unsigned mask = (1u << shift) - 1u;
  #pragma unroll
  for (int q = 0; q < IT; q++){
    int i = tid + q * 256;
    if (i < cnt){
      int k = keys[start + i], v = vals[start + i];
      b[q] = k >> shift;
      rc[q] = ((unsigned)v << shift) | ((unsigned)k & mask);
      rank[q] = atomicAdd(&hist[b[q]], 1);
    } else b[q] = -1;
  }
  __syncthreads();
  int lane = tid & 63, wid = tid >> 6;
  if (wid == 0){
    int h0 = hist[lane*4], h1 = hist[lane*4+1], h2 = hist[lane*4+2], h3 = hist[lane*4+3];
    int s = h0 + h1 + h2 + h3;
    int sc = s;
    #pragma unroll
    for (int o = 1; o < 64; o <<= 1){ int t = __shfl_up(sc, (unsigned)o, 64); if (lane >= o) sc += t; }
    int base = sc - s;
    excl[lane*4] = base; excl[lane*4+1] = base + h0;
    excl[lane*4+2] = base + h0 + h1; excl[lane*4+3] = base + h0 + h1 + h2;
  }
  __syncthreads();
  #pragma unroll
  for (int q = 0; q < IT; q++){
    if (b[q] >= 0){
      int pos = excl[b[q]] + rank[q];
      recs[pos] = rc[q];
      binid[pos] = (unsigned char)b[q];
    }
  }
  if (tid < nb && hist[tid] > 0) gbase[tid] = atomicAdd(&cursor[tid], hist[tid]);
  __syncthreads();
  for (int i = tid; i < cnt; i += 256){
    int bb = binid[i];
    rec_out[gbase[bb] + (i - excl[bb])] = recs[i];
  }
}

// ---------------- per-bucket CSR build: off/inv/csr, all atomics in LDS ----------------
template<int LOC>
__global__ __launch_bounds__(256) void build_csr(const unsigned* __restrict__ rec, const int* __restrict__ bbase,
    int nkeys, int E, int* __restrict__ off, float* __restrict__ inv, int* __restrict__ csr){
  constexpr int LB = (LOC == 128) ? 7 : 9;
  __shared__ int hist[LOC];
  __shared__ int excl[LOC];
  __shared__ int cur[LOC];
  __shared__ int wsum[8];
  int b = blockIdx.x, tid = threadIdx.x;
  int s = bbase[b], e = bbase[b + 1];
  for (int k = tid; k < LOC; k += 256){ hist[k] = 0; cur[k] = 0; }
  __syncthreads();
  for (int i = s + tid; i < e; i += 256) atomicAdd(&hist[rec[i] & (LOC - 1)], 1);
  __syncthreads();
  int lane = tid & 63, wid = tid >> 6;
  constexpr int BPT = (LOC + 255) / 256;
  int h[BPT]; int ssum = 0;
  #pragma unroll
  for (int q = 0; q < BPT; q++){
    int k = tid * BPT + q;
    h[q] = (k < LOC) ? hist[k] : 0;
    ssum += h[q];
  }
  int sc = ssum;
  #pragma unroll
  for (int o = 1; o < 64; o <<= 1){ int t = __shfl_up(sc, (unsigned)o, 64); if (lane >= o) sc += t; }
  if (lane == 63) wsum[wid] = sc;
  __syncthreads();
  int base = 0;
  for (int w = 0; w < wid; w++) base += wsum[w];
  int ex = base + sc - ssum;
  #pragma unroll
  for (int q = 0; q < BPT; q++){
    int k = tid * BPT + q;
    if (k < LOC) excl[k] = ex;
    ex += h[q];
  }
  __syncthreads();
  int keybase = b << LB;
  for (int k = tid; k < LOC; k += 256){
    int gk = keybase + k;
    if (gk < nkeys){
      off[gk] = s + excl[k];
      int c = hist[k];
      inv[gk] = 1.0f / (float)(c > 1 ? c : 1);
    }
  }
  if (b == (int)gridDim.x - 1 && tid == 0) off[nkeys] = E;
  for (int i = s + tid; i < e; i += 256){
    unsigned r = rec[i];
    int k = (int)(r & (LOC - 1));
    int rk = atomicAdd(&cur[k], 1);
    csr[s + excl[k] + rk] = (int)(r >> LB);
  }
}

// ---------------- weight pre-pack: W[K][128] fp32 -> WT hi[128][K], lo[128][K] bf16 ----------------
struct PackArgs {
  const float* src[10];
  short* dst[10];
  int K[10];
  int start[11];
};
__global__ __launch_bounds__(256) void pack_w(PackArgs pa){
  int t = blockIdx.x * 256 + threadIdx.x;
  if (t >= pa.start[10]) return;
  int m = 0;
  #pragma unroll
  for (int i = 1; i < 10; i++) if (t >= pa.start[i]) m = i;
  int local = t - pa.start[m];
  int k = local >> 7, n = local & 127;
  float w = pa.src[m][local];
  unsigned short hs = bf_rne(w);
  float hf = __uint_as_float((unsigned)hs << 16);
  unsigned short ls = bf_rne(w - hf);
  short* d = pa.dst[m];
  int Km = pa.K[m];
  d[n * Km + k] = (short)hs;
  d[128 * Km + n * Km + k] = (short)ls;
}

// ---------------- fused MFMA GEMM: OUT = [relu?][l2norm?](A@Wl + bias [+ Bs@Wr]) ----------------
template<int KA, bool DUAL, bool NORM, bool RELU>
__global__ __launch_bounds__(512) void sage_mfma(
    const float* __restrict__ A, const float* __restrict__ Bs,
    const short* __restrict__ WlT, const short* __restrict__ WrT,
    const float* __restrict__ bias, float* __restrict__ OUT, int M)
{
  constexpr int KST = KA / 32;
  const int wid  = threadIdx.x >> 6;
  const int lane = threadIdx.x & 63;
  const int l15  = lane & 15;
  const int lkg  = lane >> 4;
  const int ncol0 = wid * 16;

  bf16x8 wl_hi[KST], wl_lo[KST];
  {
    const short* bh = WlT + (size_t)(ncol0 + l15) * KA + lkg * 8;
    #pragma unroll
    for (int ks = 0; ks < KST; ks++){
      wl_hi[ks] = *(const bf16x8*)(bh + ks * 32);
      wl_lo[ks] = *(const bf16x8*)(bh + 128 * KA + ks * 32);
    }
  }
  bf16x8 wr_hi[DUAL ? KST : 1], wr_lo[DUAL ? KST : 1];
  if (DUAL){
    const short* bh = WrT + (size_t)(ncol0 + l15) * 128 + lkg * 8;
    #pragma unroll
    for (int ks = 0; ks < (DUAL ? KST : 1); ks++){
      wr_hi[ks] = *(const bf16x8*)(bh + ks * 32);
      wr_lo[ks] = *(const bf16x8*)(bh + 128 * 128 + ks * 32);
    }
  }
  const float bb = bias[ncol0 + l15];

  __shared__ float red[8][16];

  for (int row0 = blockIdx.x * 16; row0 < M; row0 += gridDim.x * 16){
    int ar = row0 + l15; if (ar > M - 1) ar = M - 1;
    f32x4 acc = {0.f, 0.f, 0.f, 0.f};
    {
      const float* ap = A + (size_t)ar * KA + lkg * 8;
      #pragma unroll
      for (int ks = 0; ks < KST; ks++){
        f32x4 a0 = *(const f32x4*)(ap + ks * 32);
        f32x4 a1 = *(const f32x4*)(ap + ks * 32 + 4);
        bf16x8 hi, lo;
        cvt_hilo(a0, a1, hi, lo);
        acc = mfma16(hi, wl_hi[ks], acc);
        acc = mfma16(hi, wl_lo[ks], acc);
        acc = mfma16(lo, wl_hi[ks], acc);
      }
    }
    if (DUAL){
      const float* bp = Bs + (size_t)ar * 128 + lkg * 8;
      #pragma unroll
      for (int ks = 0; ks < (DUAL ? KST : 1); ks++){
        f32x4 a0 = *(const f32x4*)(bp + ks * 32);
        f32x4 a1 = *(const f32x4*)(bp + ks * 32 + 4);
        bf16x8 hi, lo;
        cvt_hilo(a0, a1, hi, lo);
        acc = mfma16(hi, wr_hi[ks], acc);
        acc = mfma16(hi, wr_lo[ks], acc);
        acc = mfma16(lo, wr_hi[ks], acc);
      }
    }
    acc.x += bb; acc.y += bb; acc.z += bb; acc.w += bb;

    if (NORM){
      float s4[4];
      #pragma unroll
      for (int r = 0; r < 4; r++){
        float v = acc[r] * acc[r];
        v += __shfl_xor(v, 1, 64);
        v += __shfl_xor(v, 2, 64);
        v += __shfl_xor(v, 4, 64);
        v += __shfl_xor(v, 8, 64);
        s4[r] = v;
      }
      if (l15 == 0){
        #pragma unroll
        for (int r = 0; r < 4; r++) red[wid][lkg * 4 + r] = s4[r];
      }
      __syncthreads();
      #pragma unroll
      for (int r = 0; r < 4; r++){
        float s = 0.f;
        #pragma unroll
        for (int w2 = 0; w2 < 8; w2++) s += red[w2][lkg * 4 + r];
        float scale = 1.f / fmaxf(sqrtf(s), 1e-12f);
        acc[r] *= scale;
      }
      __syncthreads();
    }
    if (RELU){
      acc.x = fmaxf(acc.x, 0.f); acc.y = fmaxf(acc.y, 0.f);
      acc.z = fmaxf(acc.z, 0.f); acc.w = fmaxf(acc.w, 0.f);
    }
    const int colg = ncol0 + l15;
    #pragma unroll
    for (int r = 0; r < 4; r++){
      int row = row0 + lkg * 4 + r;
      if (row < M) OUT[(size_t)row * H + colg] = acc[r];
    }
  }
}

// ---------------- segment mean via CSR: half-wave (32 lanes x float4), 4-deep unroll ----------------
__global__ __launch_bounds__(256) void agg_kernel(const float* __restrict__ feat, const int* __restrict__ csr,
                           const int* __restrict__ off, const float* __restrict__ inv,
                           float* __restrict__ out, int n){
  int gw = (blockIdx.x * 256 + threadIdx.x) >> 5;
  int li = threadIdx.x & 31;
  if (gw >= n) return;
  int s = off[gw], e = off[gw + 1];
  f32x4 acc0 = {0.f,0.f,0.f,0.f}, acc1 = {0.f,0.f,0.f,0.f};
  f32x4 acc2 = {0.f,0.f,0.f,0.f}, acc3 = {0.f,0.f,0.f,0.f};
  int i = s;
  for (; i + 3 < e; i += 4){
    int i0 = csr[i], i1 = csr[i+1], i2 = csr[i+2], i3 = csr[i+3];
    acc0 += *(const f32x4*)&feat[(size_t)i0 * H + li * 4];
    acc1 += *(const f32x4*)&feat[(size_t)i1 * H + li * 4];
    acc2 += *(const f32x4*)&feat[(size_t)i2 * H + li * 4];
    acc3 += *(const f32x4*)&feat[(size_t)i3 * H + li * 4];
  }
  for (; i < e; i++){
    acc0 += *(const f32x4*)&feat[(size_t)csr[i] * H + li * 4];
  }
  float iv = inv[gw];
  f32x4 r = (acc0 + acc1) + (acc2 + acc3);
  r.x *= iv; r.y *= iv; r.z *= iv; r.w *= iv;
  *(f32x4*)&out[(size_t)gw * H + li * 4] = r;
}

// ---------------- link predictor: half-wave per pair ----------------
__global__ __launch_bounds__(256) void dot_kernel(const float* __restrict__ zt, const float* __restrict__ zp,
                           const int* __restrict__ ls, const int* __restrict__ ld,
                           float* __restrict__ out, int n){
  int w = (blockIdx.x * 256 + threadIdx.x) >> 5;
  int li = threadIdx.x & 31;
  if (w >= n) return;
  int a = ls[w], b = ld[w];
  f32x4 x = *(const f32x4*)&zt[(size_t)a * H + li * 4];
  f32x4 y = *(const f32x4*)&zp[(size_t)b * H + li * 4];
  float v = x.x * y.x + x.y * y.y + x.z * y.z + x.w * y.w;
  v += __shfl_xor(v, 1, 64);
  v += __shfl_xor(v, 2, 64);
  v += __shfl_xor(v, 4, 64);
  v += __shfl_xor(v, 8, 64);
  v += __shfl_xor(v, 16, 64);
  if (li == 0) out[w] = v;
}

extern "C" void kernel_launch(void* const* d_in, const int* in_sizes, int n_in,
                              void* d_out, int out_size, void* d_ws, size_t ws_size,
                              hipStream_t stream){
  const float* x_t  = (const float*)d_in[0];
  const float* x_p  = (const float*)d_in[1];
  const int*   esrc = (const int*)d_in[2];
  const int*   edst = (const int*)d_in[3];
  const int*   lsrc = (const int*)d_in[4];
  const int*   ldst = (const int*)d_in[5];
  const float* Wn_t = (const float*)d_in[6];
  const float* bn_t = (const float*)d_in[7];
  const float* Wn_p = (const float*)d_in[8];
  const float* bn_p = (const float*)d_in[9];
  const float* W1_l_p=(const float*)d_in[10]; const float* b1_p=(const float*)d_in[11]; const float* W1_r_p=(const float*)d_in[12];
  const float* W1_l_t=(const float*)d_in[13]; const float* b1_t=(const float*)d_in[14]; const float* W1_r_t=(const float*)d_in[15];
  const float* W2_l_p=(const float*)d_in[16]; const float* b2_p=(const float*)d_in[17]; const float* W2_r_p=(const float*)d_in[18];
  const float* W2_l_t=(const float*)d_in[19]; const float* b2_t=(const float*)d_in[20]; const float* W2_r_t=(const float*)d_in[21];
  float* out = (float*)d_out;

  const int FT = 128, FP = 64;
  int NT = in_sizes[0] / FT;
  int NP = in_sizes[1] / FP;
  int E  = in_sizes[2];
  int EL = in_sizes[4];

  const int SH_P = 7, SH_T = 9;
  int nb_p = (NP + (1 << SH_P) - 1) >> SH_P;   // 157
  int nb_t = (NT + (1 << SH_T) - 1) >> SH_T;   // 196

  char* base = (char*)d_ws;
  size_t o = 0;
  auto alloc = [&](size_t bytes) -> char* { char* p = base + o; o = align_up(o + bytes, 256); return p; };
  int*   cb_p  = (int*)alloc(256 * 4);
  int*   cb_t  = (int*)alloc(256 * 4);
  size_t zero_bytes = o;
  int*   bb_p  = (int*)alloc(260 * 4);
  int*   bb_t  = (int*)alloc(260 * 4);
  int*   cu_p  = (int*)alloc(256 * 4);
  int*   cu_t  = (int*)alloc(256 * 4);
  int*   off_p = (int*)alloc((size_t)(NP + 1) * 4);
  int*   off_t = (int*)alloc((size_t)(NT + 1) * 4);
  float* inv_p = (float*)alloc((size_t)NP * 4);
  float* inv_t = (float*)alloc((size_t)NT * 4);
  unsigned* rec_p = (unsigned*)alloc((size_t)E * 4);
  unsigned* rec_t = (unsigned*)alloc((size_t)E * 4);
  int*   csr_p = (int*)alloc((size_t)E * 4);
  int*   csr_t = (int*)alloc((size_t)E * 4);
  float* h_t   = (float*)alloc((size_t)NT * H * 4);
  float* h_p   = (float*)alloc((size_t)NP * H * 4);
  float* a_t   = (float*)alloc((size_t)NT * H * 4);
  float* a_p   = (float*)alloc((size_t)NP * H * 4);

  PackArgs pa;
  const float* wsrc[10] = {Wn_t, Wn_p, W1_l_p, W1_r_p, W1_l_t, W1_r_t, W2_l_p, W2_r_p, W2_l_t, W2_r_t};
  int Ks[10] = {128, 64, 128, 128, 128, 128, 128, 128, 128, 128};
  short* wpk[10];
  int st = 0;
  for (int m = 0; m < 10; m++){
    wpk[m] = (short*)alloc((size_t)2 * 128 * Ks[m] * sizeof(short));
    pa.src[m] = wsrc[m]; pa.dst[m] = wpk[m]; pa.K[m] = Ks[m]; pa.start[m] = st;
    st += Ks[m] * 128;
  }
  pa.start[10] = st;
  (void)ws_size; (void)n_in; (void)out_size;

  hipMemsetAsync(base, 0, zero_bytes, stream);
  pack_w<<<(st + 255) / 256, 256, 0, stream>>>(pa);

  // CSR build: bucket hist -> bases -> LDS-sorted binning -> per-bucket CSR
  hist_buckets<<<512, 256, 0, stream>>>(esrc, edst, E, cb_p, cb_t);
  scan_buckets<<<1, 64, 0, stream>>>(cb_p, cb_t, nb_p, nb_t, bb_p, bb_t, cu_p, cu_t);
  int nchunks = (E + 4095) / 4096;
  bin_edges<<<nchunks, 256, 0, stream>>>(edst, esrc, E, SH_P, nb_p, cu_p, rec_p);
  bin_edges<<<nchunks, 256, 0, stream>>>(esrc, edst, E, SH_T, nb_t, cu_t, rec_t);
  build_csr<128><<<nb_p, 256, 0, stream>>>(rec_p, bb_p, NP, E, off_p, inv_p, csr_p);
  build_csr<512><<<nb_t, 256, 0, stream>>>(rec_t, bb_t, NT, E, off_t, inv_t, csr_t);

  // input projections
  sage_mfma<128,false,false,false><<<(NT + 15) / 16, 512, 0, stream>>>(x_t, nullptr, wpk[0], nullptr, bn_t, h_t, NT);
  sage_mfma<64, false,false,false><<<(NP + 15) / 16, 512, 0, stream>>>(x_p, nullptr, wpk[1], nullptr, bn_p, h_p, NP);

  // layer 1
  agg_kernel<<<(NP + 7) / 8, 256, 0, stream>>>(h_t, csr_p, off_p, inv_p, a_p, NP);
  agg_kernel<<<(NT + 7) / 8, 256, 0, stream>>>(h_p, csr_t, off_t, inv_t, a_t, NT);
  sage_mfma<128,true,true,true><<<(NP + 15) / 16, 512, 0, stream>>>(a_p, h_p, wpk[2], wpk[3], b1_p, a_p, NP);
  sage_mfma<128,true,true,true><<<(NT + 15) / 16, 512, 0, stream>>>(a_t, h_t, wpk[4], wpk[5], b1_t, a_t, NT);

  // layer 2
  agg_kernel<<<(NP + 7) / 8, 256, 0, stream>>>(a_t, csr_p, off_p, inv_p, h_p, NP);
  agg_kernel<<<(NT + 7) / 8, 256, 0, stream>>>(a_p, csr_t, off_t, inv_t, h_t, NT);
  sage_mfma<128,true,true,false><<<(NP + 15) / 16, 512, 0, stream>>>(h_p, a_p, wpk[6], wpk[7], b2_p, h_p, NP);
  sage_mfma<128,true,true,false><<<(NT + 15) / 16, 512, 0, stream>>>(h_t, a_t, wpk[8], wpk[9], b2_t, h_t, NT);

  // link prediction
  dot_kernel<<<(EL + 7) / 8, 256, 0, stream>>>(h_t, h_p, lsrc, ldst, out, EL);
}

// Round 4
// 1152.524 us; speedup vs baseline: 1.5990x; 1.0815x over previous
//
#include <hip/hip_runtime.h>
#include <hip/hip_bf16.h>

#define H 128

typedef __attribute__((ext_vector_type(8))) short bf16x8;
typedef __attribute__((ext_vector_type(4))) float f32x4;
typedef __attribute__((ext_vector_type(4))) unsigned short u16x4;

static inline size_t align_up(size_t x, size_t a){ return (x + a - 1) & ~(a - 1); }

__device__ inline f32x4 mfma16(bf16x8 a, bf16x8 b, f32x4 c){
  return __builtin_amdgcn_mfma_f32_16x16x32_bf16(a, b, c, 0, 0, 0);
}

__device__ inline unsigned short bf_rne(float v){
  unsigned u = __float_as_uint(v);
  unsigned r = u + 0x7fffu + ((u >> 16) & 1u);
  return (unsigned short)(r >> 16);
}
__device__ inline float bf2f(unsigned short u){
  return __uint_as_float((unsigned)u << 16);
}

__device__ inline void cvt_hilo(const f32x4& a0, const f32x4& a1, bf16x8& hi, bf16x8& lo){
  #pragma unroll
  for (int e = 0; e < 8; e++){
    float v = (e < 4) ? a0[e] : a1[e - 4];
    unsigned short hs = bf_rne(v);
    float hf = bf2f(hs);
    hi[e] = (short)hs;
    lo[e] = (short)bf_rne(v - hf);
  }
}

// ---------------- bucket histograms (coarse): dst>>7, src>>9 ----------------
__global__ __launch_bounds__(256) void hist_buckets(const int* __restrict__ src, const int* __restrict__ dst,
    int E, int* __restrict__ cnt_b_p, int* __restrict__ cnt_b_t){
  __shared__ int hp[256], ht[256];
  int tid = threadIdx.x;
  hp[tid] = 0; ht[tid] = 0;
  __syncthreads();
  for (int i = blockIdx.x * 256 + tid; i < E; i += gridDim.x * 256){
    atomicAdd(&hp[dst[i] >> 7], 1);
    atomicAdd(&ht[src[i] >> 9], 1);
  }
  __syncthreads();
  if (hp[tid]) atomicAdd(&cnt_b_p[tid], hp[tid]);
  if (ht[tid]) atomicAdd(&cnt_b_t[tid], ht[tid]);
}

// ---------------- tiny scan of bucket counts -> bases + cursors ----------------
__global__ void scan_buckets(const int* __restrict__ cb_p, const int* __restrict__ cb_t, int nbp, int nbt,
                             int* __restrict__ base_p, int* __restrict__ base_t,
                             int* __restrict__ cur_p, int* __restrict__ cur_t){
  if (threadIdx.x == 0){
    int s = 0;
    for (int i = 0; i < nbp; i++){ base_p[i] = s; cur_p[i] = s; s += cb_p[i]; }
    base_p[nbp] = s;
  } else if (threadIdx.x == 1){
    int s = 0;
    for (int i = 0; i < nbt; i++){ base_t[i] = s; cur_t[i] = s; s += cb_t[i]; }
    base_t[nbt] = s;
  }
}

// ---------------- bin edges into coarse buckets via per-block LDS counting sort ----------------
__global__ __launch_bounds__(256) void bin_edges(const int* __restrict__ keys, const int* __restrict__ vals,
    int E, int shift, int nb, int* __restrict__ cursor, unsigned* __restrict__ rec_out){
  const int CH = 4096, IT = 16;
  __shared__ int hist[256];
  __shared__ int excl[256];
  __shared__ int gbase[256];
  __shared__ unsigned recs[CH];
  __shared__ unsigned char binid[CH];
  int tid = threadIdx.x;
  int start = blockIdx.x * CH;
  int cnt = E - start; if (cnt > CH) cnt = CH;
  if (cnt <= 0) return;
  hist[tid] = 0;
  __syncthreads();
  int b[IT]; int rank[IT]; unsigned rc[IT];
  unsigned mask = (1u << shift) - 1u;
  #pragma unroll
  for (int q = 0; q < IT; q++){
    int i = tid + q * 256;
    if (i < cnt){
      int k = keys[start + i], v = vals[start + i];
      b[q] = k >> shift;
      rc[q] = ((unsigned)v << shift) | ((unsigned)k & mask);
      rank[q] = atomicAdd(&hist[b[q]], 1);
    } else b[q] = -1;
  }
  __syncthreads();
  int lane = tid & 63, wid = tid >> 6;
  if (wid == 0){
    int h0 = hist[lane*4], h1 = hist[lane*4+1], h2 = hist[lane*4+2], h3 = hist[lane*4+3];
    int s = h0 + h1 + h2 + h3;
    int sc = s;
    #pragma unroll
    for (int o = 1; o < 64; o <<= 1){ int t = __shfl_up(sc, (unsigned)o, 64); if (lane >= o) sc += t; }
    int base = sc - s;
    excl[lane*4] = base; excl[lane*4+1] = base + h0;
    excl[lane*4+2] = base + h0 + h1; excl[lane*4+3] = base + h0 + h1 + h2;
  }
  __syncthreads();
  #pragma unroll
  for (int q = 0; q < IT; q++){
    if (b[q] >= 0){
      int pos = excl[b[q]] + rank[q];
      recs[pos] = rc[q];
      binid[pos] = (unsigned char)b[q];
    }
  }
  if (tid < nb && hist[tid] > 0) gbase[tid] = atomicAdd(&cursor[tid], hist[tid]);
  __syncthreads();
  for (int i = tid; i < cnt; i += 256){
    int bb = binid[i];
    rec_out[gbase[bb] + (i - excl[bb])] = recs[i];
  }
}

// ---------------- per-bucket CSR build ----------------
template<int LOC>
__global__ __launch_bounds__(256) void build_csr(const unsigned* __restrict__ rec, const int* __restrict__ bbase,
    int nkeys, int E, int* __restrict__ off, float* __restrict__ inv, int* __restrict__ csr){
  constexpr int LB = (LOC == 128) ? 7 : 9;
  __shared__ int hist[LOC];
  __shared__ int excl[LOC];
  __shared__ int cur[LOC];
  __shared__ int wsum[8];
  int b = blockIdx.x, tid = threadIdx.x;
  int s = bbase[b], e = bbase[b + 1];
  for (int k = tid; k < LOC; k += 256){ hist[k] = 0; cur[k] = 0; }
  __syncthreads();
  for (int i = s + tid; i < e; i += 256) atomicAdd(&hist[rec[i] & (LOC - 1)], 1);
  __syncthreads();
  int lane = tid & 63, wid = tid >> 6;
  constexpr int BPT = (LOC + 255) / 256;
  int h[BPT]; int ssum = 0;
  #pragma unroll
  for (int q = 0; q < BPT; q++){
    int k = tid * BPT + q;
    h[q] = (k < LOC) ? hist[k] : 0;
    ssum += h[q];
  }
  int sc = ssum;
  #pragma unroll
  for (int o = 1; o < 64; o <<= 1){ int t = __shfl_up(sc, (unsigned)o, 64); if (lane >= o) sc += t; }
  if (lane == 63) wsum[wid] = sc;
  __syncthreads();
  int base = 0;
  for (int w = 0; w < wid; w++) base += wsum[w];
  int ex = base + sc - ssum;
  #pragma unroll
  for (int q = 0; q < BPT; q++){
    int k = tid * BPT + q;
    if (k < LOC) excl[k] = ex;
    ex += h[q];
  }
  __syncthreads();
  int keybase = b << LB;
  for (int k = tid; k < LOC; k += 256){
    int gk = keybase + k;
    if (gk < nkeys){
      off[gk] = s + excl[k];
      int c = hist[k];
      inv[gk] = 1.0f / (float)(c > 1 ? c : 1);
    }
  }
  if (b == (int)gridDim.x - 1 && tid == 0) off[nkeys] = E;
  for (int i = s + tid; i < e; i += 256){
    unsigned r = rec[i];
    int k = (int)(r & (LOC - 1));
    int rk = atomicAdd(&cur[k], 1);
    csr[s + excl[k] + rk] = (int)(r >> LB);
  }
}

// ---------------- weight pre-pack ----------------
struct PackArgs {
  const float* src[10];
  short* dst[10];
  int K[10];
  int start[11];
};
__global__ __launch_bounds__(256) void pack_w(PackArgs pa){
  int t = blockIdx.x * 256 + threadIdx.x;
  if (t >= pa.start[10]) return;
  int m = 0;
  #pragma unroll
  for (int i = 1; i < 10; i++) if (t >= pa.start[i]) m = i;
  int local = t - pa.start[m];
  int k = local >> 7, n = local & 127;
  float w = pa.src[m][local];
  unsigned short hs = bf_rne(w);
  float hf = bf2f(hs);
  unsigned short ls = bf_rne(w - hf);
  short* d = pa.dst[m];
  int Km = pa.K[m];
  d[n * Km + k] = (short)hs;
  d[128 * Km + n * Km + k] = (short)ls;
}

// ---------------- fused MFMA GEMM ----------------
// A: CVT ? fp32 [M][KA] : bf16 hi/lo [M][2*KA]. Bs: bf16 [M][256]. OUT: bf16 [M][256].
// 8 waves; wave = 16 output cols; 32 rows (2 MFMA row-tiles) per iteration; grid-stride.
template<int KA, bool CVT, bool DUAL, bool NORM, bool RELU>
__global__ __launch_bounds__(512) void sage_mfma(
    const void* __restrict__ Ain, const unsigned short* __restrict__ Bs,
    const short* __restrict__ WlT, const short* __restrict__ WrT,
    const float* __restrict__ bias, unsigned short* __restrict__ OUT, int M, int tiles)
{
  constexpr int KST = KA / 32;
  const int wid  = threadIdx.x >> 6;
  const int lane = threadIdx.x & 63;
  const int l15  = lane & 15;
  const int lkg  = lane >> 4;
  const int ncol0 = wid * 16;

  bf16x8 wl_hi[KST], wl_lo[KST];
  {
    const short* bh = WlT + (size_t)(ncol0 + l15) * KA + lkg * 8;
    #pragma unroll
    for (int ks = 0; ks < KST; ks++){
      wl_hi[ks] = *(const bf16x8*)(bh + ks * 32);
      wl_lo[ks] = *(const bf16x8*)(bh + 128 * KA + ks * 32);
    }
  }
  bf16x8 wr_hi[DUAL ? 4 : 1], wr_lo[DUAL ? 4 : 1];
  if (DUAL){
    const short* bh = WrT + (size_t)(ncol0 + l15) * 128 + lkg * 8;
    #pragma unroll
    for (int ks = 0; ks < (DUAL ? 4 : 1); ks++){
      wr_hi[ks] = *(const bf16x8*)(bh + ks * 32);
      wr_lo[ks] = *(const bf16x8*)(bh + 128 * 128 + ks * 32);
    }
  }
  const float bb = bias[ncol0 + l15];
  const int colg = ncol0 + l15;

  __shared__ float red[2][8][32];
  int parity = 0;

  for (int t0 = blockIdx.x; t0 < tiles; t0 += gridDim.x, parity ^= 1){
    int row0 = t0 * 32;
    f32x4 acc[2];
    acc[0] = (f32x4){0.f,0.f,0.f,0.f};
    acc[1] = (f32x4){0.f,0.f,0.f,0.f};
    #pragma unroll
    for (int tt = 0; tt < 2; tt++){
      int ar = row0 + tt * 16 + l15; if (ar > M - 1) ar = M - 1;
      if (CVT){
        const float* ap = (const float*)Ain + (size_t)ar * KA + lkg * 8;
        #pragma unroll
        for (int ks = 0; ks < KST; ks++){
          f32x4 a0 = *(const f32x4*)(ap + ks * 32);
          f32x4 a1 = *(const f32x4*)(ap + ks * 32 + 4);
          bf16x8 hi, lo;
          cvt_hilo(a0, a1, hi, lo);
          acc[tt] = mfma16(hi, wl_hi[ks], acc[tt]);
          acc[tt] = mfma16(hi, wl_lo[ks], acc[tt]);
          acc[tt] = mfma16(lo, wl_hi[ks], acc[tt]);
        }
      } else {
        const unsigned short* ap = (const unsigned short*)Ain + (size_t)ar * (2 * KA) + lkg * 8;
        #pragma unroll
        for (int ks = 0; ks < KST; ks++){
          bf16x8 hi = *(const bf16x8*)(ap + ks * 32);
          bf16x8 lo = *(const bf16x8*)(ap + KA + ks * 32);
          acc[tt] = mfma16(hi, wl_hi[ks], acc[tt]);
          acc[tt] = mfma16(hi, wl_lo[ks], acc[tt]);
          acc[tt] = mfma16(lo, wl_hi[ks], acc[tt]);
        }
      }
      if (DUAL){
        const unsigned short* bp = Bs + (size_t)ar * 256 + lkg * 8;
        #pragma unroll
        for (int ks = 0; ks < (DUAL ? 4 : 1); ks++){
          bf16x8 hi = *(const bf16x8*)(bp + ks * 32);
          bf16x8 lo = *(const bf16x8*)(bp + 128 + ks * 32);
          acc[tt] = mfma16(hi, wr_hi[ks], acc[tt]);
          acc[tt] = mfma16(hi, wr_lo[ks], acc[tt]);
          acc[tt] = mfma16(lo, wr_hi[ks], acc[tt]);
        }
      }
      acc[tt].x += bb; acc[tt].y += bb; acc[tt].z += bb; acc[tt].w += bb;
    }

    if (NORM){
      #pragma unroll
      for (int tt = 0; tt < 2; tt++){
        #pragma unroll
        for (int r = 0; r < 4; r++){
          float v = acc[tt][r] * acc[tt][r];
          v += __shfl_xor(v, 1, 64);
          v += __shfl_xor(v, 2, 64);
          v += __shfl_xor(v, 4, 64);
          v += __shfl_xor(v, 8, 64);
          if (l15 == 0) red[parity][wid][tt * 16 + lkg * 4 + r] = v;
        }
      }
      __syncthreads();
      #pragma unroll
      for (int tt = 0; tt < 2; tt++){
        #pragma unroll
        for (int r = 0; r < 4; r++){
          int idx = tt * 16 + lkg * 4 + r;
          float s = 0.f;
          #pragma unroll
          for (int w2 = 0; w2 < 8; w2++) s += red[parity][w2][idx];
          float scale = 1.f / fmaxf(sqrtf(s), 1e-12f);
          acc[tt][r] *= scale;
        }
      }
    }
    if (RELU){
      #pragma unroll
      for (int tt = 0; tt < 2; tt++){
        acc[tt].x = fmaxf(acc[tt].x, 0.f); acc[tt].y = fmaxf(acc[tt].y, 0.f);
        acc[tt].z = fmaxf(acc[tt].z, 0.f); acc[tt].w = fmaxf(acc[tt].w, 0.f);
      }
    }
    #pragma unroll
    for (int tt = 0; tt < 2; tt++){
      #pragma unroll
      for (int r = 0; r < 4; r++){
        int row = row0 + tt * 16 + lkg * 4 + r;
        if (row < M){
          float v = acc[tt][r];
          unsigned short hs = bf_rne(v);
          unsigned short ls = bf_rne(v - bf2f(hs));
          OUT[(size_t)row * 256 + colg] = hs;
          OUT[(size_t)row * 256 + 128 + colg] = ls;
        }
      }
    }
  }
}

// ---------------- segment mean via CSR: half-wave per dst row, bf16 hi/lo in/out ----------------
__device__ inline f32x4 u4f(u16x4 u){
  f32x4 r;
  r.x = bf2f(u.x); r.y = bf2f(u.y); r.z = bf2f(u.z); r.w = bf2f(u.w);
  return r;
}
__global__ __launch_bounds__(256) void agg_kernel(const unsigned short* __restrict__ feat, const int* __restrict__ csr,
                           const int* __restrict__ off, const float* __restrict__ inv,
                           unsigned short* __restrict__ out, int n){
  int gw = (blockIdx.x * 256 + threadIdx.x) >> 5;
  int li = threadIdx.x & 31;
  if (gw >= n) return;
  int s = off[gw], e = off[gw + 1];
  f32x4 a0 = {0.f,0.f,0.f,0.f}, a1 = {0.f,0.f,0.f,0.f};
  f32x4 a2 = {0.f,0.f,0.f,0.f}, a3 = {0.f,0.f,0.f,0.f};
  int i = s;
  for (; i + 1 < e; i += 2){
    size_t r0 = (size_t)csr[i] * 256, r1 = (size_t)csr[i+1] * 256;
    u16x4 h0 = *(const u16x4*)&feat[r0 + li * 4];
    u16x4 l0 = *(const u16x4*)&feat[r0 + 128 + li * 4];
    u16x4 h1 = *(const u16x4*)&feat[r1 + li * 4];
    u16x4 l1 = *(const u16x4*)&feat[r1 + 128 + li * 4];
    a0 += u4f(h0); a1 += u4f(l0); a2 += u4f(h1); a3 += u4f(l1);
  }
  if (i < e){
    size_t r0 = (size_t)csr[i] * 256;
    u16x4 h0 = *(const u16x4*)&feat[r0 + li * 4];
    u16x4 l0 = *(const u16x4*)&feat[r0 + 128 + li * 4];
    a0 += u4f(h0); a1 += u4f(l0);
  }
  float iv = inv[gw];
  f32x4 r = (a0 + a1) + (a2 + a3);
  r.x *= iv; r.y *= iv; r.z *= iv; r.w *= iv;
  u16x4 hv, lv;
  #pragma unroll
  for (int q = 0; q < 4; q++){
    unsigned short hs = bf_rne(r[q]);
    hv[q] = hs;
    lv[q] = bf_rne(r[q] - bf2f(hs));
  }
  *(u16x4*)&out[(size_t)gw * 256 + li * 4] = hv;
  *(u16x4*)&out[(size_t)gw * 256 + 128 + li * 4] = lv;
}

// ---------------- link predictor: half-wave per pair, hi/lo reconstruct ----------------
__global__ __launch_bounds__(256) void dot_kernel(const unsigned short* __restrict__ zt, const unsigned short* __restrict__ zp,
                           const int* __restrict__ ls, const int* __restrict__ ld,
                           float* __restrict__ out, int n){
  int w = (blockIdx.x * 256 + threadIdx.x) >> 5;
  int li = threadIdx.x & 31;
  if (w >= n) return;
  size_t ra = (size_t)ls[w] * 256, rb = (size_t)ld[w] * 256;
  u16x4 th = *(const u16x4*)&zt[ra + li * 4];
  u16x4 tl = *(const u16x4*)&zt[ra + 128 + li * 4];
  u16x4 ph = *(const u16x4*)&zp[rb + li * 4];
  u16x4 pl = *(const u16x4*)&zp[rb + 128 + li * 4];
  f32x4 x = u4f(th) + u4f(tl);
  f32x4 y = u4f(ph) + u4f(pl);
  float v = x.x * y.x + x.y * y.y + x.z * y.z + x.w * y.w;
  v += __shfl_xor(v, 1, 64);
  v += __shfl_xor(v, 2, 64);
  v += __shfl_xor(v, 4, 64);
  v += __shfl_xor(v, 8, 64);
  v += __shfl_xor(v, 16, 64);
  if (li == 0) out[w] = v;
}

extern "C" void kernel_launch(void* const* d_in, const int* in_sizes, int n_in,
                              void* d_out, int out_size, void* d_ws, size_t ws_size,
                              hipStream_t stream){
  const float* x_t  = (const float*)d_in[0];
  const float* x_p  = (const float*)d_in[1];
  const int*   esrc = (const int*)d_in[2];
  const int*   edst = (const int*)d_in[3];
  const int*   lsrc = (const int*)d_in[4];
  const int*   ldst = (const int*)d_in[5];
  const float* Wn_t = (const float*)d_in[6];
  const float* bn_t = (const float*)d_in[7];
  const float* Wn_p = (const float*)d_in[8];
  const float* bn_p = (const float*)d_in[9];
  const float* W1_l_p=(const float*)d_in[10]; const float* b1_p=(const float*)d_in[11]; const float* W1_r_p=(const float*)d_in[12];
  const float* W1_l_t=(const float*)d_in[13]; const float* b1_t=(const float*)d_in[14]; const float* W1_r_t=(const float*)d_in[15];
  const float* W2_l_p=(const float*)d_in[16]; const float* b2_p=(const float*)d_in[17]; const float* W2_r_p=(const float*)d_in[18];
  const float* W2_l_t=(const float*)d_in[19]; const float* b2_t=(const float*)d_in[20]; const float* W2_r_t=(const float*)d_in[21];
  float* out = (float*)d_out;

  const int FT = 128, FP = 64;
  int NT = in_sizes[0] / FT;
  int NP = in_sizes[1] / FP;
  int E  = in_sizes[2];
  int EL = in_sizes[4];

  const int SH_P = 7, SH_T = 9;
  int nb_p = (NP + (1 << SH_P) - 1) >> SH_P;
  int nb_t = (NT + (1 << SH_T) - 1) >> SH_T;

  char* base = (char*)d_ws;
  size_t o = 0;
  auto alloc = [&](size_t bytes) -> char* { char* p = base + o; o = align_up(o + bytes, 256); return p; };
  int*   cb_p  = (int*)alloc(256 * 4);
  int*   cb_t  = (int*)alloc(256 * 4);
  size_t zero_bytes = o;
  int*   bb_p  = (int*)alloc(260 * 4);
  int*   bb_t  = (int*)alloc(260 * 4);
  int*   cu_p  = (int*)alloc(256 * 4);
  int*   cu_t  = (int*)alloc(256 * 4);
  int*   off_p = (int*)alloc((size_t)(NP + 1) * 4);
  int*   off_t = (int*)alloc((size_t)(NT + 1) * 4);
  float* inv_p = (float*)alloc((size_t)NP * 4);
  float* inv_t = (float*)alloc((size_t)NT * 4);
  unsigned* rec_p = (unsigned*)alloc((size_t)E * 4);
  unsigned* rec_t = (unsigned*)alloc((size_t)E * 4);
  int*   csr_p = (int*)alloc((size_t)E * 4);
  int*   csr_t = (int*)alloc((size_t)E * 4);
  unsigned short* h_t = (unsigned short*)alloc((size_t)NT * 256 * 2);
  unsigned short* h_p = (unsigned short*)alloc((size_t)NP * 256 * 2);
  unsigned short* a_t = (unsigned short*)alloc((size_t)NT * 256 * 2);
  unsigned short* a_p = (unsigned short*)alloc((size_t)NP * 256 * 2);

  PackArgs pa;
  const float* wsrc[10] = {Wn_t, Wn_p, W1_l_p, W1_r_p, W1_l_t, W1_r_t, W2_l_p, W2_r_p, W2_l_t, W2_r_t};
  int Ks[10] = {128, 64, 128, 128, 128, 128, 128, 128, 128, 128};
  short* wpk[10];
  int st = 0;
  for (int m = 0; m < 10; m++){
    wpk[m] = (short*)alloc((size_t)2 * 128 * Ks[m] * sizeof(short));
    pa.src[m] = wsrc[m]; pa.dst[m] = wpk[m]; pa.K[m] = Ks[m]; pa.start[m] = st;
    st += Ks[m] * 128;
  }
  pa.start[10] = st;
  (void)ws_size; (void)n_in; (void)out_size;

  hipMemsetAsync(base, 0, zero_bytes, stream);
  pack_w<<<(st + 255) / 256, 256, 0, stream>>>(pa);

  // CSR build
  hist_buckets<<<512, 256, 0, stream>>>(esrc, edst, E, cb_p, cb_t);
  scan_buckets<<<1, 64, 0, stream>>>(cb_p, cb_t, nb_p, nb_t, bb_p, bb_t, cu_p, cu_t);
  int nchunks = (E + 4095) / 4096;
  bin_edges<<<nchunks, 256, 0, stream>>>(edst, esrc, E, SH_P, nb_p, cu_p, rec_p);
  bin_edges<<<nchunks, 256, 0, stream>>>(esrc, edst, E, SH_T, nb_t, cu_t, rec_t);
  build_csr<128><<<nb_p, 256, 0, stream>>>(rec_p, bb_p, NP, E, off_p, inv_p, csr_p);
  build_csr<512><<<nb_t, 256, 0, stream>>>(rec_t, bb_t, NT, E, off_t, inv_t, csr_t);

  int tiles_t = (NT + 31) / 32;
  int tiles_p = (NP + 31) / 32;
  int grid_t = tiles_t < 1024 ? tiles_t : 1024;
  int grid_p = tiles_p < 1024 ? tiles_p : 1024;

  // input projections (fp32 A with in-kernel cvt)
  sage_mfma<128,true,false,false,false><<<grid_t, 512, 0, stream>>>(x_t, nullptr, wpk[0], nullptr, bn_t, h_t, NT, tiles_t);
  sage_mfma<64, true,false,false,false><<<grid_p, 512, 0, stream>>>(x_p, nullptr, wpk[1], nullptr, bn_p, h_p, NP, tiles_p);

  // layer 1
  agg_kernel<<<(NP + 7) / 8, 256, 0, stream>>>(h_t, csr_p, off_p, inv_p, a_p, NP);
  agg_kernel<<<(NT + 7) / 8, 256, 0, stream>>>(h_p, csr_t, off_t, inv_t, a_t, NT);
  sage_mfma<128,false,true,true,true><<<grid_p, 512, 0, stream>>>(a_p, h_p, wpk[2], wpk[3], b1_p, a_p, NP, tiles_p);
  sage_mfma<128,false,true,true,true><<<grid_t, 512, 0, stream>>>(a_t, h_t, wpk[4], wpk[5], b1_t, a_t, NT, tiles_t);

  // layer 2
  agg_kernel<<<(NP + 7) / 8, 256, 0, stream>>>(a_t, csr_p, off_p, inv_p, h_p, NP);
  agg_kernel<<<(NT + 7) / 8, 256, 0, stream>>>(a_p, csr_t, off_t, inv_t, h_t, NT);
  sage_mfma<128,false,true,true,false><<<grid_p, 512, 0, stream>>>(h_p, a_p, wpk[6], wpk[7], b2_p, h_p, NP, tiles_p);
  sage_mfma<128,false,true,true,false><<<grid_t, 512, 0, stream>>>(h_t, a_t, wpk[8], wpk[9], b2_t, h_t, NT, tiles_t);

  // link prediction
  dot_kernel<<<(EL + 7) / 8, 256, 0, stream>>>(h_t, h_p, lsrc, ldst, out, EL);
}